// Round 2
// baseline (1017.647 us; speedup 1.0000x reference)
//
#include <hip/hip_runtime.h>
#include <hip/hip_bf16.h>
#include <hip/hip_fp16.h>

// LSTM_Encoder pipeline (dtype-agnostic: runtime-sniffs fp32 vs bf16 inputs):
//   sniff -> flag in ws      (1 thread; fp32-as-bf16 shows huge exponents)
//   pairs/senlen/embed/pack  (prep; only these + span touch external floats)
//   gemm_bt(x0,Wc0) -> xg    (MFMA bf16, M=4096 N=1600 K=576; xg stored bf16)
//   rec(layer0)              (64 blocks = batch x dir, VGPR-resident f16 weights)
//   gemm_bt(x1,Wc1) -> xg    (K=416)
//   rec(layer1) -> hs1 (f32)
//   span                     (writes 205/410 MB, HBM-bound)

typedef unsigned short u16;
typedef unsigned int u32;
typedef short shortx8 __attribute__((ext_vector_type(8)));
typedef float floatx4 __attribute__((ext_vector_type(4)));
typedef _Float16 half2v __attribute__((ext_vector_type(2)));

#define B_ 32
#define L_ 128
#define H_ 200
#define K0P 576
#define K1P 416
#define NG 1600
#define NPAIR 8001
#define SPAN_ELEMS 102412800  // 32*8001*400

__device__ __forceinline__ float bf2f(u16 v) {
  u32 u = ((u32)v) << 16;
  return __builtin_bit_cast(float, u);
}
__device__ __forceinline__ u16 f2bf(float f) {
  __hip_bfloat16 h = __float2bfloat16(f);
  return __builtin_bit_cast(u16, h);
}
__device__ __forceinline__ float loadF(const void* p, int idx, int isf32) {
  return isf32 ? ((const float*)p)[idx] : bf2f(((const u16*)p)[idx]);
}
__device__ __forceinline__ float dot2h(u32 w, u32 h, float acc) {
#if __has_builtin(__builtin_amdgcn_fdot2)
  return __builtin_amdgcn_fdot2(__builtin_bit_cast(half2v, w),
                                __builtin_bit_cast(half2v, h), acc, false);
#else
  half2v a = __builtin_bit_cast(half2v, w), b = __builtin_bit_cast(half2v, h);
  return acc + (float)a.x * (float)b.x + (float)a.y * (float)b.y;
#endif
}
__device__ __forceinline__ float sigf(float x) { return 1.f / (1.f + __expf(-x)); }
__device__ __forceinline__ float tanhff(float x) {
  x = fminf(fmaxf(x, -15.f), 15.f);
  float e = __expf(-2.f * x);
  return (1.f - e) / (1.f + e);
}

// ---------- dtype sniff: fp32 mantissa-halves read as bf16 have random exponents ----------

__global__ void sniff_kernel(const void* __restrict__ Ew, int* __restrict__ flag) {
  if (threadIdx.x != 0) return;
  const u16* p = (const u16*)Ew;
  int big = 0;
  for (int i = 0; i < 128; ++i) {
    int e = (p[i] >> 7) & 0xFF;
    if (e >= 0x84) big++;  // |bf16| >= 32: never for 0.1*N(0,1) data, ~48% for random bits
  }
  *flag = (big >= 4) ? 1 : 0;
}

// ---------- prep kernels ----------

__global__ void pairs_kernel(int* pa, int* pb) {
  int a = threadIdx.x;
  if (a >= 126) return;
  int off = a * 126 - a * (a - 1) / 2;
  for (int b = a + 1; b <= 126; ++b) {
    pa[off] = a;
    pb[off] = b;
    ++off;
  }
}

__global__ void senlen_kernel(const int* __restrict__ word, void* __restrict__ out,
                              const int* __restrict__ flag) {
  int b = threadIdx.x;
  if (b >= B_) return;
  int cnt = 0;
  for (int l = 0; l < L_; ++l) cnt += (word[b * L_ + l] != 0);
  float v = (float)(cnt - 2);
  if (*flag) ((float*)out)[SPAN_ELEMS + b] = v;
  else ((u16*)out)[SPAN_ELEMS + b] = f2bf(v);
}

__global__ void embed_kernel(const int* __restrict__ lang, const int* __restrict__ word,
                             const int* __restrict__ pos, const int* __restrict__ dep,
                             const int* __restrict__ ent, const int* __restrict__ iob,
                             const void* __restrict__ El, const void* __restrict__ Ew,
                             const void* __restrict__ Ep, const void* __restrict__ Ed,
                             const void* __restrict__ Ee, const void* __restrict__ Ei,
                             u16* __restrict__ x0, const int* __restrict__ flag) {
  int row = blockIdx.x;          // row = l*32 + b  (x[l][b] = emb[b][l])
  int isf32 = *flag;
  int l = row >> 5, b = row & 31;
  int io = b * L_ + l;
  int li = lang[io], wi = word[io], pi = pos[io], di = dep[io], ei = ent[io], ii = iob[io];
  for (int c = threadIdx.x; c < K0P; c += 64) {
    float v = 0.f;
    if (c < 50) v = loadF(El, li * 50 + c, isf32);
    else if (c < 350) v = loadF(Ew, wi * 300 + (c - 50), isf32);
    else if (c < 400) v = loadF(Ep, pi * 50 + (c - 350), isf32);
    else if (c < 450) v = loadF(Ed, di * 50 + (c - 400), isf32);
    else if (c < 500) v = loadF(Ee, ei * 50 + (c - 450), isf32);
    else if (c < 550) v = loadF(Ei, ii * 50 + (c - 500), isf32);
    x0[row * K0P + c] = f2bf(v);
  }
}

__global__ void pack_kernel(const void* __restrict__ Wih0, const void* __restrict__ Whh0,
                            const void* __restrict__ bih0, const void* __restrict__ bhh0,
                            const void* __restrict__ Wih1, const void* __restrict__ Whh1,
                            const void* __restrict__ bih1, const void* __restrict__ bhh1,
                            u16* __restrict__ Wc0, u16* __restrict__ Wc1,
                            float* __restrict__ bias0, float* __restrict__ bias1,
                            u16* __restrict__ Whf, u16* __restrict__ x1,
                            const int* __restrict__ flag) {
  int idx = blockIdx.x * 256 + threadIdx.x;
  int isf32 = *flag;
  if (idx < 1600 * K0P) {  // Wc0: rows (dir*800+g), cols padded 550->576
    int r = idx / K0P, c = idx - r * K0P;
    Wc0[idx] = (c < 550) ? f2bf(loadF(Wih0, r * 550 + c, isf32)) : (u16)0;
    return;
  }
  idx -= 1600 * K0P;
  if (idx < 1600 * K1P) {  // Wc1: cols padded 400->416
    int r = idx / K1P, c = idx - r * K1P;
    Wc1[idx] = (c < 400) ? f2bf(loadF(Wih1, r * 400 + c, isf32)) : (u16)0;
    return;
  }
  idx -= 1600 * K1P;
  if (idx < 1600) { bias0[idx] = loadF(bih0, idx, isf32) + loadF(bhh0, idx, isf32); return; }
  idx -= 1600;
  if (idx < 1600) { bias1[idx] = loadF(bih1, idx, isf32) + loadF(bhh1, idx, isf32); return; }
  idx -= 1600;
  if (idx < 640000) {  // Whh -> f16, [layer][dir][800][200]
    float s = (idx < 320000) ? loadF(Whh0, idx, isf32) : loadF(Whh1, idx - 320000, isf32);
    _Float16 h = (_Float16)s;
    Whf[idx] = __builtin_bit_cast(u16, h);
    return;
  }
  idx -= 640000;
  if (idx < 4096 * 16) {  // zero-pad x1 cols 400..415
    int row = idx >> 4, c = idx & 15;
    x1[row * K1P + 400 + c] = 0;
  }
}

// ---------- GEMM: C[M,1600](bf16) = A[M,Ks](bf16) * W[1600,Ks]^T + bias ----------

__global__ __launch_bounds__(256) void gemm_bt(const u16* __restrict__ A, const u16* __restrict__ W,
                                               const float* __restrict__ bias, u16* __restrict__ C,
                                               int Ks) {
  __shared__ __align__(16) u16 As[64 * 40];  // stride 40 shorts = 80 B (16B-aligned rows)
  __shared__ __align__(16) u16 Bs[64 * 40];
  int tid = threadIdx.x;
  int n0 = blockIdx.x * 64, m0 = blockIdx.y * 64;
  int lane = tid & 63, wv = tid >> 6, ln = lane & 15, quad = lane >> 4;
  floatx4 acc[4] = {{0.f, 0.f, 0.f, 0.f}, {0.f, 0.f, 0.f, 0.f}, {0.f, 0.f, 0.f, 0.f}, {0.f, 0.f, 0.f, 0.f}};
  int arow = tid >> 2, acs = (tid & 3) * 8;
  const u16* Ag = A + (size_t)(m0 + arow) * Ks + acs;
  const u16* Wg = W + (size_t)(n0 + arow) * Ks + acs;
  for (int k0 = 0; k0 < Ks; k0 += 32) {
    __syncthreads();
    *(uint4*)&As[arow * 40 + acs] = *(const uint4*)(Ag + k0);
    *(uint4*)&Bs[arow * 40 + acs] = *(const uint4*)(Wg + k0);
    __syncthreads();
    shortx8 af = *(const shortx8*)&As[(wv * 16 + ln) * 40 + quad * 8];
    shortx8 b0 = *(const shortx8*)&Bs[(ln) * 40 + quad * 8];
    shortx8 b1 = *(const shortx8*)&Bs[(16 + ln) * 40 + quad * 8];
    shortx8 b2 = *(const shortx8*)&Bs[(32 + ln) * 40 + quad * 8];
    shortx8 b3 = *(const shortx8*)&Bs[(48 + ln) * 40 + quad * 8];
    acc[0] = __builtin_amdgcn_mfma_f32_16x16x32_bf16(af, b0, acc[0], 0, 0, 0);
    acc[1] = __builtin_amdgcn_mfma_f32_16x16x32_bf16(af, b1, acc[1], 0, 0, 0);
    acc[2] = __builtin_amdgcn_mfma_f32_16x16x32_bf16(af, b2, acc[2], 0, 0, 0);
    acc[3] = __builtin_amdgcn_mfma_f32_16x16x32_bf16(af, b3, acc[3], 0, 0, 0);
  }
  int rbase = m0 + wv * 16 + quad * 4;  // C/D: col=lane&15, row=quad*4+reg (m89-verified)
#pragma unroll
  for (int ns = 0; ns < 4; ++ns) {
    int cg = n0 + ns * 16 + ln;
    float bv = bias[cg];
#pragma unroll
    for (int r = 0; r < 4; ++r) {
      C[(size_t)(rbase + r) * NG + cg] = f2bf(acc[ns][r] + bv);
    }
  }
}

// ---------- recurrence: 64 blocks = (batch, dir), weights VGPR-resident ----------

__global__ __launch_bounds__(448) void rec_kernel(const u16* __restrict__ xg, const u16* __restrict__ Whf,
                                                  int layer, u16* __restrict__ x1, float* __restrict__ hs) {
  int tid = threadIdx.x;
  int batch = blockIdx.x >> 1, dir = blockIdx.x & 1;
  __shared__ __align__(16) u16 hsh[H_];   // h as f16
  __shared__ float gsh[800];
  uint4 wA[25], wB[25];                   // 2 rows x 200 f16 = 200 VGPRs
  if (tid < 400) {
    const uint4* wa = (const uint4*)(Whf + (size_t)((layer * 2 + dir) * 800 + tid) * 200);
    const uint4* wb = (const uint4*)(Whf + (size_t)((layer * 2 + dir) * 800 + tid + 400) * 200);
#pragma unroll
    for (int i = 0; i < 25; ++i) { wA[i] = wa[i]; wB[i] = wb[i]; }
  }
  float cst = 0.f;
  if (tid < H_) hsh[tid] = 0;
  __syncthreads();
  for (int t = 0; t < L_; ++t) {
    int tt = dir ? (L_ - 1 - t) : t;
    if (tid < 400) {
      const u16* xgrow = xg + (size_t)(tt * B_ + batch) * NG + dir * 800;
      float a0 = bf2f(xgrow[tid]);        // rows 0..399  (gates i/f)
      float a1 = bf2f(xgrow[tid + 400]);  // rows 400..799 (gates g/o)
      const uint4* hv4 = (const uint4*)hsh;
#pragma unroll
      for (int kk = 0; kk < 25; ++kk) {
        uint4 hv = hv4[kk];  // broadcast read
        a0 = dot2h(wA[kk].x, hv.x, a0);
        a0 = dot2h(wA[kk].y, hv.y, a0);
        a0 = dot2h(wA[kk].z, hv.z, a0);
        a0 = dot2h(wA[kk].w, hv.w, a0);
        a1 = dot2h(wB[kk].x, hv.x, a1);
        a1 = dot2h(wB[kk].y, hv.y, a1);
        a1 = dot2h(wB[kk].z, hv.z, a1);
        a1 = dot2h(wB[kk].w, hv.w, a1);
      }
      gsh[tid] = a0;
      gsh[tid + 400] = a1;
    }
    __syncthreads();
    if (tid < H_) {
      float gi = gsh[tid], gf = gsh[200 + tid], gg = gsh[400 + tid], go = gsh[600 + tid];
      cst = sigf(gf) * cst + sigf(gi) * tanhff(gg);
      float h = sigf(go) * tanhff(cst);
      _Float16 hh = (_Float16)h;
      hsh[tid] = __builtin_bit_cast(u16, hh);
      int orow = tt * B_ + batch;
      if (layer == 0) {
        x1[(size_t)orow * K1P + dir * H_ + tid] = f2bf(h);
      } else {
        hs[(size_t)orow * 400 + dir * H_ + tid] = h;
      }
    }
    __syncthreads();
  }
}

// ---------- span output: out[bb][p][0:400] ----------

__global__ void span_kernel(const float* __restrict__ hs, const int* __restrict__ pa,
                            const int* __restrict__ pb, void* __restrict__ outp,
                            const int* __restrict__ flag) {
  int bb = blockIdx.y;
  int p0 = blockIdx.x * 16;
  int tid = threadIdx.x;
  int isf32 = *flag;
  for (int idx = tid; idx < 16 * 200; idx += 256) {
    int p = p0 + idx / 200;
    if (p >= NPAIR) return;
    int dd2 = idx - (idx / 200) * 200;
    int dd = dd2 * 2;
    int a = pa[p], b = pb[p];
    // dd<200: f[b]-f[a]; dd>=200: bw[a+1]-bw[b+1]; same hs column dd both cases
    int r1 = (dd < 200) ? b : (a + 1);
    int r2 = (dd < 200) ? a : (b + 1);
    const float* h1 = hs + (size_t)(r1 * B_ + bb) * 400 + dd;
    const float* h2 = hs + (size_t)(r2 * B_ + bb) * 400 + dd;
    float v0 = h1[0] - h2[0];
    float v1 = h1[1] - h2[1];
    size_t o2 = (size_t)(bb * NPAIR + p) * 200 + dd2;
    if (isf32) {
      ((float2*)outp)[o2] = make_float2(v0, v1);
    } else {
      ((u32*)outp)[o2] = (u32)f2bf(v0) | ((u32)f2bf(v1) << 16);
    }
  }
}

// ---------- launch ----------

extern "C" void kernel_launch(void* const* d_in, const int* in_sizes, int n_in,
                              void* d_out, int out_size, void* d_ws, size_t ws_size,
                              hipStream_t stream) {
  const int* lang = (const int*)d_in[0];
  const int* word = (const int*)d_in[1];
  const int* pos = (const int*)d_in[2];
  const int* dep = (const int*)d_in[3];
  const int* ent = (const int*)d_in[4];
  const int* iob = (const int*)d_in[5];

  char* ws = (char*)d_ws;
  int* flag = (int*)(ws + 0);
  int* pa = (int*)(ws + 4096);
  int* pb = (int*)(ws + 36864);
  u16* x0 = (u16*)(ws + 69632);            // 4096x576 bf16
  u16* Wc0 = (u16*)(ws + 4788224);         // 1600x576 bf16
  u16* Wc1 = (u16*)(ws + 6631424);         // 1600x416 bf16
  float* bias0 = (float*)(ws + 7962624);   // 1600 f32
  float* bias1 = (float*)(ws + 7969024);
  u16* Whf = (u16*)(ws + 7975424);         // 2x2x800x200 f16
  u16* x1 = (u16*)(ws + 9255424);          // 4096x416 bf16
  float* hs1 = (float*)(ws + 12663296);    // 4096x400 f32
  u16* xg = (u16*)(ws + 19216896);         // 4096x1600 bf16 (end ~32.3 MB)

  hipLaunchKernelGGL(sniff_kernel, dim3(1), dim3(64), 0, stream, d_in[7], flag);
  hipLaunchKernelGGL(pairs_kernel, dim3(1), dim3(128), 0, stream, pa, pb);
  hipLaunchKernelGGL(senlen_kernel, dim3(1), dim3(64), 0, stream, word, d_out, flag);
  hipLaunchKernelGGL(embed_kernel, dim3(4096), dim3(64), 0, stream,
                     lang, word, pos, dep, ent, iob,
                     d_in[6], d_in[7], d_in[8], d_in[9], d_in[10], d_in[11], x0, flag);
  hipLaunchKernelGGL(pack_kernel, dim3(8969), dim3(256), 0, stream,
                     d_in[12], d_in[13], d_in[14], d_in[15],
                     d_in[16], d_in[17], d_in[18], d_in[19],
                     Wc0, Wc1, bias0, bias1, Whf, x1, flag);
  hipLaunchKernelGGL(gemm_bt, dim3(25, 64), dim3(256), 0, stream, x0, Wc0, bias0, xg, K0P);
  hipLaunchKernelGGL(rec_kernel, dim3(64), dim3(448), 0, stream, xg, Whf, 0, x1, hs1);
  hipLaunchKernelGGL(gemm_bt, dim3(25, 64), dim3(256), 0, stream, x1, Wc1, bias1, xg, K1P);
  hipLaunchKernelGGL(rec_kernel, dim3(64), dim3(448), 0, stream, xg, Whf, 1, x1, hs1);
  hipLaunchKernelGGL(span_kernel, dim3(501, 32), dim3(256), 0, stream, hs1, pa, pb, d_out, flag);
}

// Round 3
// 964.133 us; speedup vs baseline: 1.0555x; 1.0555x over previous
//
#include <hip/hip_runtime.h>
#include <hip/hip_bf16.h>
#include <hip/hip_fp16.h>

// LSTM_Encoder pipeline (dtype-agnostic: runtime-sniffs fp32 vs bf16 inputs):
//   prep (sniff+pairs+senlen fused) / embed / pack
//   gemm_bt(x0,Wc0) -> xg    (MFMA bf16, M=4096 N=1600 K=576; xg stored bf16)
//   rec(layer0)              (64 blocks = batch x dir, VGPR-resident f16 weights,
//                             xg prefetched one step ahead of the dot chain)
//   gemm_bt(x1,Wc1) -> xg    (K=416)
//   rec(layer1) -> hs1 (f32)
//   span                     (float4 I/O, writes 410 MB f32 / 205 MB bf16, HBM-bound)

typedef unsigned short u16;
typedef unsigned int u32;
typedef short shortx8 __attribute__((ext_vector_type(8)));
typedef float floatx4 __attribute__((ext_vector_type(4)));
typedef _Float16 half2v __attribute__((ext_vector_type(2)));

#define B_ 32
#define L_ 128
#define H_ 200
#define K0P 576
#define K1P 416
#define NG 1600
#define NPAIR 8001
#define SPAN_ELEMS 102412800  // 32*8001*400

__device__ __forceinline__ float bf2f(u16 v) {
  u32 u = ((u32)v) << 16;
  return __builtin_bit_cast(float, u);
}
__device__ __forceinline__ u16 f2bf(float f) {
  __hip_bfloat16 h = __float2bfloat16(f);
  return __builtin_bit_cast(u16, h);
}
__device__ __forceinline__ float loadF(const void* p, int idx, int isf32) {
  return isf32 ? ((const float*)p)[idx] : bf2f(((const u16*)p)[idx]);
}
__device__ __forceinline__ float dot2h(u32 w, u32 h, float acc) {
#if __has_builtin(__builtin_amdgcn_fdot2)
  return __builtin_amdgcn_fdot2(__builtin_bit_cast(half2v, w),
                                __builtin_bit_cast(half2v, h), acc, false);
#else
  half2v a = __builtin_bit_cast(half2v, w), b = __builtin_bit_cast(half2v, h);
  return acc + (float)a.x * (float)b.x + (float)a.y * (float)b.y;
#endif
}
__device__ __forceinline__ float sigf(float x) { return 1.f / (1.f + __expf(-x)); }
__device__ __forceinline__ float tanhff(float x) {
  x = fminf(fmaxf(x, -15.f), 15.f);
  float e = __expf(-2.f * x);
  return (1.f - e) / (1.f + e);
}

// ---------- fused prep: sniff (t0) + pairs (t<126) + senlen (t128..159) ----------

__global__ void prep_kernel(const void* __restrict__ Ew, const int* __restrict__ word,
                            int* __restrict__ flag, int* __restrict__ pa, int* __restrict__ pb,
                            void* __restrict__ out) {
  __shared__ int sflag;
  int tid = threadIdx.x;
  if (tid == 0) {
    const u16* p = (const u16*)Ew;
    int big = 0;
    for (int i = 0; i < 128; ++i) {
      int e = (p[i] >> 7) & 0xFF;
      if (e >= 0x84) big++;  // |bf16| >= 32: never for 0.1*N(0,1), ~48% for fp32 raw halves
    }
    int f = (big >= 4) ? 1 : 0;
    *flag = f;
    sflag = f;
  }
  if (tid < 126) {
    int a = tid;
    int off = a * 126 - a * (a - 1) / 2;
    for (int b = a + 1; b <= 126; ++b) {
      pa[off] = a;
      pb[off] = b;
      ++off;
    }
  }
  __syncthreads();
  if (tid >= 128 && tid < 128 + B_) {
    int b = tid - 128;
    int cnt = 0;
    for (int l = 0; l < L_; ++l) cnt += (word[b * L_ + l] != 0);
    float v = (float)(cnt - 2);
    if (sflag) ((float*)out)[SPAN_ELEMS + b] = v;
    else ((u16*)out)[SPAN_ELEMS + b] = f2bf(v);
  }
}

// ---------- embedding gather ----------

__global__ void embed_kernel(const int* __restrict__ lang, const int* __restrict__ word,
                             const int* __restrict__ pos, const int* __restrict__ dep,
                             const int* __restrict__ ent, const int* __restrict__ iob,
                             const void* __restrict__ El, const void* __restrict__ Ew,
                             const void* __restrict__ Ep, const void* __restrict__ Ed,
                             const void* __restrict__ Ee, const void* __restrict__ Ei,
                             u16* __restrict__ x0, const int* __restrict__ flag) {
  int row = blockIdx.x;          // row = l*32 + b  (x[l][b] = emb[b][l])
  int isf32 = *flag;
  int l = row >> 5, b = row & 31;
  int io = b * L_ + l;
  int li = lang[io], wi = word[io], pi = pos[io], di = dep[io], ei = ent[io], ii = iob[io];
  for (int c = threadIdx.x; c < K0P; c += 64) {
    float v = 0.f;
    if (c < 50) v = loadF(El, li * 50 + c, isf32);
    else if (c < 350) v = loadF(Ew, wi * 300 + (c - 50), isf32);
    else if (c < 400) v = loadF(Ep, pi * 50 + (c - 350), isf32);
    else if (c < 450) v = loadF(Ed, di * 50 + (c - 400), isf32);
    else if (c < 500) v = loadF(Ee, ei * 50 + (c - 450), isf32);
    else if (c < 550) v = loadF(Ei, ii * 50 + (c - 500), isf32);
    x0[row * K0P + c] = f2bf(v);
  }
}

// ---------- weight repack ----------

__global__ void pack_kernel(const void* __restrict__ Wih0, const void* __restrict__ Whh0,
                            const void* __restrict__ bih0, const void* __restrict__ bhh0,
                            const void* __restrict__ Wih1, const void* __restrict__ Whh1,
                            const void* __restrict__ bih1, const void* __restrict__ bhh1,
                            u16* __restrict__ Wc0, u16* __restrict__ Wc1,
                            float* __restrict__ bias0, float* __restrict__ bias1,
                            u16* __restrict__ Whf, u16* __restrict__ x1,
                            const int* __restrict__ flag) {
  int idx = blockIdx.x * 256 + threadIdx.x;
  int isf32 = *flag;
  if (idx < 1600 * K0P) {  // Wc0: rows (dir*800+g), cols padded 550->576
    int r = idx / K0P, c = idx - r * K0P;
    Wc0[idx] = (c < 550) ? f2bf(loadF(Wih0, r * 550 + c, isf32)) : (u16)0;
    return;
  }
  idx -= 1600 * K0P;
  if (idx < 1600 * K1P) {  // Wc1: cols padded 400->416
    int r = idx / K1P, c = idx - r * K1P;
    Wc1[idx] = (c < 400) ? f2bf(loadF(Wih1, r * 400 + c, isf32)) : (u16)0;
    return;
  }
  idx -= 1600 * K1P;
  if (idx < 1600) { bias0[idx] = loadF(bih0, idx, isf32) + loadF(bhh0, idx, isf32); return; }
  idx -= 1600;
  if (idx < 1600) { bias1[idx] = loadF(bih1, idx, isf32) + loadF(bhh1, idx, isf32); return; }
  idx -= 1600;
  if (idx < 640000) {  // Whh -> f16, [layer][dir][800][200]
    float s = (idx < 320000) ? loadF(Whh0, idx, isf32) : loadF(Whh1, idx - 320000, isf32);
    _Float16 h = (_Float16)s;
    Whf[idx] = __builtin_bit_cast(u16, h);
    return;
  }
  idx -= 640000;
  if (idx < 4096 * 16) {  // zero-pad x1 cols 400..415
    int row = idx >> 4, c = idx & 15;
    x1[row * K1P + 400 + c] = 0;
  }
}

// ---------- GEMM: C[M,1600](bf16) = A[M,Ks](bf16) * W[1600,Ks]^T + bias ----------

__global__ __launch_bounds__(256) void gemm_bt(const u16* __restrict__ A, const u16* __restrict__ W,
                                               const float* __restrict__ bias, u16* __restrict__ C,
                                               int Ks) {
  __shared__ __align__(16) u16 As[64 * 40];  // stride 40 shorts = 80 B (2-way conflict max = free)
  __shared__ __align__(16) u16 Bs[64 * 40];
  int tid = threadIdx.x;
  int n0 = blockIdx.x * 64, m0 = blockIdx.y * 64;
  int lane = tid & 63, wv = tid >> 6, ln = lane & 15, quad = lane >> 4;
  floatx4 acc[4] = {{0.f, 0.f, 0.f, 0.f}, {0.f, 0.f, 0.f, 0.f}, {0.f, 0.f, 0.f, 0.f}, {0.f, 0.f, 0.f, 0.f}};
  int arow = tid >> 2, acs = (tid & 3) * 8;
  const u16* Ag = A + (size_t)(m0 + arow) * Ks + acs;
  const u16* Wg = W + (size_t)(n0 + arow) * Ks + acs;
  for (int k0 = 0; k0 < Ks; k0 += 32) {
    __syncthreads();
    *(uint4*)&As[arow * 40 + acs] = *(const uint4*)(Ag + k0);
    *(uint4*)&Bs[arow * 40 + acs] = *(const uint4*)(Wg + k0);
    __syncthreads();
    shortx8 af = *(const shortx8*)&As[(wv * 16 + ln) * 40 + quad * 8];
    shortx8 b0 = *(const shortx8*)&Bs[(ln) * 40 + quad * 8];
    shortx8 b1 = *(const shortx8*)&Bs[(16 + ln) * 40 + quad * 8];
    shortx8 b2 = *(const shortx8*)&Bs[(32 + ln) * 40 + quad * 8];
    shortx8 b3 = *(const shortx8*)&Bs[(48 + ln) * 40 + quad * 8];
    acc[0] = __builtin_amdgcn_mfma_f32_16x16x32_bf16(af, b0, acc[0], 0, 0, 0);
    acc[1] = __builtin_amdgcn_mfma_f32_16x16x32_bf16(af, b1, acc[1], 0, 0, 0);
    acc[2] = __builtin_amdgcn_mfma_f32_16x16x32_bf16(af, b2, acc[2], 0, 0, 0);
    acc[3] = __builtin_amdgcn_mfma_f32_16x16x32_bf16(af, b3, acc[3], 0, 0, 0);
  }
  int rbase = m0 + wv * 16 + quad * 4;  // C/D: col=lane&15, row=quad*4+reg (m89-verified)
#pragma unroll
  for (int ns = 0; ns < 4; ++ns) {
    int cg = n0 + ns * 16 + ln;
    float bv = bias[cg];
#pragma unroll
    for (int r = 0; r < 4; ++r) {
      C[(size_t)(rbase + r) * NG + cg] = f2bf(acc[ns][r] + bv);
    }
  }
}

// ---------- recurrence: 64 blocks = (batch, dir), weights VGPR-resident ----------
// Per step: prefetch xg[t+1] (hides ~L2/HBM latency behind the 100-deep fdot2 chain),
// 4 independent accumulator chains, h broadcast via LDS (f16).

__global__ __launch_bounds__(448, 2) void rec_kernel(const u16* __restrict__ xg, const u16* __restrict__ Whf,
                                                     int layer, u16* __restrict__ x1, float* __restrict__ hs) {
  int tid = threadIdx.x;
  int batch = blockIdx.x >> 1, dir = blockIdx.x & 1;
  __shared__ __align__(16) u16 hsh[H_];   // h as f16
  __shared__ float gsh[800];
  uint4 wA[25], wB[25];                   // 2 rows x 200 f16 = 200 VGPRs
  if (tid < 400) {
    const uint4* wa = (const uint4*)(Whf + (size_t)((layer * 2 + dir) * 800 + tid) * 200);
    const uint4* wb = (const uint4*)(Whf + (size_t)((layer * 2 + dir) * 800 + tid + 400) * 200);
#pragma unroll
    for (int i = 0; i < 25; ++i) { wA[i] = wa[i]; wB[i] = wb[i]; }
  }
  float cst = 0.f;
  if (tid < H_) hsh[tid] = 0;
  int rstep = (dir ? -B_ : B_) * NG;
  const u16* xr = xg + (size_t)((dir ? (L_ - 1) * B_ : 0) + batch) * NG + dir * 800;
  float a0 = 0.f, a1 = 0.f;
  if (tid < 400) { a0 = bf2f(xr[tid]); a1 = bf2f(xr[tid + 400]); }
  __syncthreads();
  for (int t = 0; t < L_; ++t) {
    int tt = dir ? (L_ - 1 - t) : t;
    float n0 = 0.f, n1 = 0.f;
    if (tid < 400) {
      if (t + 1 < L_) {  // prefetch next step's xg before the dot chain
        const u16* xn = xr + (ptrdiff_t)(t + 1) * rstep;
        n0 = bf2f(xn[tid]);
        n1 = bf2f(xn[tid + 400]);
      }
      float c0 = 0.f, c1 = 0.f;  // second accumulator pair (shorter dep chains)
      const uint4* hv4 = (const uint4*)hsh;
#pragma unroll
      for (int kk = 0; kk < 25; kk += 2) {
        uint4 hv = hv4[kk];  // broadcast read (free)
        a0 = dot2h(wA[kk].x, hv.x, a0);
        a0 = dot2h(wA[kk].y, hv.y, a0);
        a0 = dot2h(wA[kk].z, hv.z, a0);
        a0 = dot2h(wA[kk].w, hv.w, a0);
        a1 = dot2h(wB[kk].x, hv.x, a1);
        a1 = dot2h(wB[kk].y, hv.y, a1);
        a1 = dot2h(wB[kk].z, hv.z, a1);
        a1 = dot2h(wB[kk].w, hv.w, a1);
        if (kk + 1 < 25) {
          uint4 hw = hv4[kk + 1];
          c0 = dot2h(wA[kk + 1].x, hw.x, c0);
          c0 = dot2h(wA[kk + 1].y, hw.y, c0);
          c0 = dot2h(wA[kk + 1].z, hw.z, c0);
          c0 = dot2h(wA[kk + 1].w, hw.w, c0);
          c1 = dot2h(wB[kk + 1].x, hw.x, c1);
          c1 = dot2h(wB[kk + 1].y, hw.y, c1);
          c1 = dot2h(wB[kk + 1].z, hw.z, c1);
          c1 = dot2h(wB[kk + 1].w, hw.w, c1);
        }
      }
      gsh[tid] = a0 + c0;
      gsh[tid + 400] = a1 + c1;
    }
    __syncthreads();
    if (tid < H_) {
      float gi = gsh[tid], gf = gsh[200 + tid], gg = gsh[400 + tid], go = gsh[600 + tid];
      cst = sigf(gf) * cst + sigf(gi) * tanhff(gg);
      float h = sigf(go) * tanhff(cst);
      _Float16 hh = (_Float16)h;
      hsh[tid] = __builtin_bit_cast(u16, hh);
      int orow = tt * B_ + batch;
      if (layer == 0) {
        x1[(size_t)orow * K1P + dir * H_ + tid] = f2bf(h);
      } else {
        hs[(size_t)orow * 400 + dir * H_ + tid] = h;
      }
    }
    a0 = n0;
    a1 = n1;
    __syncthreads();
  }
}

// ---------- span output: out[bb][p][0:400], 8 cols per thread (16B loads/stores) ----------

__global__ __launch_bounds__(256) void span_kernel(const float* __restrict__ hs, const int* __restrict__ pa,
                                                   const int* __restrict__ pb, void* __restrict__ outp,
                                                   const int* __restrict__ flag) {
  int bb = blockIdx.y;
  int p0 = blockIdx.x * 64;
  int isf32 = *flag;
  for (int idx = threadIdx.x; idx < 64 * 50; idx += 256) {
    int pr = idx / 50;           // pair within block chunk
    int q = idx - pr * 50;       // 8-col group: cols 8q..8q+7
    int p = p0 + pr;
    if (p >= NPAIR) continue;
    int a = pa[p], b = pb[p];
    int fwd = (q < 25);          // cols<200 -> f[b]-f[a]; cols>=200 -> bw[a+1]-bw[b+1]
    int r1 = fwd ? b : (a + 1);
    int r2 = fwd ? a : (b + 1);
    int col = q * 8;
    const float4* h1 = (const float4*)(hs + (size_t)(r1 * B_ + bb) * 400 + col);
    const float4* h2 = (const float4*)(hs + (size_t)(r2 * B_ + bb) * 400 + col);
    float4 x0 = h1[0], x1v = h1[1], y0 = h2[0], y1 = h2[1];
    float4 d0 = make_float4(x0.x - y0.x, x0.y - y0.y, x0.z - y0.z, x0.w - y0.w);
    float4 d1 = make_float4(x1v.x - y1.x, x1v.y - y1.y, x1v.z - y1.z, x1v.w - y1.w);
    if (isf32) {
      float4* o = (float4*)outp + (size_t)(bb * NPAIR + p) * 100 + q * 2;
      o[0] = d0;
      o[1] = d1;
    } else {
      u32 w0 = (u32)f2bf(d0.x) | ((u32)f2bf(d0.y) << 16);
      u32 w1 = (u32)f2bf(d0.z) | ((u32)f2bf(d0.w) << 16);
      u32 w2 = (u32)f2bf(d1.x) | ((u32)f2bf(d1.y) << 16);
      u32 w3 = (u32)f2bf(d1.z) | ((u32)f2bf(d1.w) << 16);
      ((uint4*)outp)[(size_t)(bb * NPAIR + p) * 50 + q] = make_uint4(w0, w1, w2, w3);
    }
  }
}

// ---------- launch ----------

extern "C" void kernel_launch(void* const* d_in, const int* in_sizes, int n_in,
                              void* d_out, int out_size, void* d_ws, size_t ws_size,
                              hipStream_t stream) {
  const int* lang = (const int*)d_in[0];
  const int* word = (const int*)d_in[1];
  const int* pos = (const int*)d_in[2];
  const int* dep = (const int*)d_in[3];
  const int* ent = (const int*)d_in[4];
  const int* iob = (const int*)d_in[5];

  char* ws = (char*)d_ws;
  int* flag = (int*)(ws + 0);
  int* pa = (int*)(ws + 4096);
  int* pb = (int*)(ws + 36864);
  u16* x0 = (u16*)(ws + 69632);            // 4096x576 bf16
  u16* Wc0 = (u16*)(ws + 4788224);         // 1600x576 bf16
  u16* Wc1 = (u16*)(ws + 6631424);         // 1600x416 bf16
  float* bias0 = (float*)(ws + 7962624);   // 1600 f32
  float* bias1 = (float*)(ws + 7969024);
  u16* Whf = (u16*)(ws + 7975424);         // 2x2x800x200 f16
  u16* x1 = (u16*)(ws + 9255424);          // 4096x416 bf16
  float* hs1 = (float*)(ws + 12663296);    // 4096x400 f32
  u16* xg = (u16*)(ws + 19216896);         // 4096x1600 bf16 (end ~32.3 MB)

  hipLaunchKernelGGL(prep_kernel, dim3(1), dim3(256), 0, stream, d_in[7], word, flag, pa, pb, d_out);
  hipLaunchKernelGGL(embed_kernel, dim3(4096), dim3(64), 0, stream,
                     lang, word, pos, dep, ent, iob,
                     d_in[6], d_in[7], d_in[8], d_in[9], d_in[10], d_in[11], x0, flag);
  hipLaunchKernelGGL(pack_kernel, dim3(8969), dim3(256), 0, stream,
                     d_in[12], d_in[13], d_in[14], d_in[15],
                     d_in[16], d_in[17], d_in[18], d_in[19],
                     Wc0, Wc1, bias0, bias1, Whf, x1, flag);
  hipLaunchKernelGGL(gemm_bt, dim3(25, 64), dim3(256), 0, stream, x0, Wc0, bias0, xg, K0P);
  hipLaunchKernelGGL(rec_kernel, dim3(64), dim3(448), 0, stream, xg, Whf, 0, x1, hs1);
  hipLaunchKernelGGL(gemm_bt, dim3(25, 64), dim3(256), 0, stream, x1, Wc1, bias1, xg, K1P);
  hipLaunchKernelGGL(rec_kernel, dim3(64), dim3(448), 0, stream, xg, Whf, 1, x1, hs1);
  hipLaunchKernelGGL(span_kernel, dim3(126, 32), dim3(256), 0, stream, hs1, pa, pb, d_out, flag);
}